// Round 14
// baseline (6951.968 us; speedup 1.0000x reference)
//
#include <hip/hip_runtime.h>
#include <stdint.h>

#define BB 128
#define TT 512
#define EE 128
#define HH 256
#define KK 32
#define WSTR  388    // f32 stride of W rows: %32==4, 16B aligned
#define SLAB  66     // f64 per A-slab: 64 + 2 pad (keeps 16B align, spreads banks)
#define MAGIC 0x13572468

typedef double f64x4 __attribute__((ext_vector_type(4)));

// Workspace: hx f32 [2par][2dir][B][H] @0 (512 KB); cnt @512K; flags @516K;
//            em f64 [B][T][K] @2M (16 MB).
#define OFF_CNT (512ull << 10)
#define OFF_FLG (516ull << 10)
#define OFF_EM  (2ull << 20)

// ---------------------------------------------------------------------------
// k_persist R13: MFMA path verified on HW (R12: PASS 6623us, MfmaUtil 20.6%
// = exactly the 6.1k-cy/step f64 MFMA floor; VALUBusy 8.4%). R12 analysis:
// GEMM is now ~6k of a 30k-cy step; the ~23k "other" (emission conflicts on
// serial path, single-MFMA-wave pipe starvation, sync slack) is the target.
// Changes (sync/cell/Viterbi/W-layout verbatim):
//  1. Emission moved AFTER the h(s) signal -> hides in next step's
//     inter-block wait slack; signal fires ~2k cy earlier.
//  2. Both GEMM phases split across all 8 waves (waves g and g+4 halve K);
//     f64 partials combined via LDS BEFORE the two preserved f32 roundings
//     (f32(Sx)+b, then +f32(Sh)). Serial MFMA depth 96->48 per wave; both
//     waves/SIMD feed the matrix pipe.
//  3. A staged in fragment-slab order AA[kb][m*4+ka] -> MFMA A-reads and
//     emission h-reads at the b64 bank floor; LwR[kk][sub][33] padded
//     replication -> emission Lw reads conflict-free (was 8-way).
// Numerics: only f64 summation ORDER changes (em order already proven
// reorder-robust by R12's absmax 0.0); every f32 rounding point unchanged.
// mode 0 fallback (discovery fails) keeps the R3 scalar GEMM on row-major
// AA view; em uses the new j-order (statistically safe).
// LDS: AA 50.7K + Wl 99.3K + Gl 4.2K + LwR 2.1K = 156.4K -> 1 block/CU.
// ---------------------------------------------------------------------------
__global__ __launch_bounds__(512, 1) void k_persist(
        const int* __restrict__ tok, const float* __restrict__ table,
        const float* __restrict__ Wihf, const float* __restrict__ Whhf,
        const float* __restrict__ bf,
        const float* __restrict__ Wihb, const float* __restrict__ Whhb,
        const float* __restrict__ bb,
        const float* __restrict__ lw,
        float* __restrict__ hx, int* __restrict__ cnt,
        double* __restrict__ em, int* __restrict__ flags) {
    __shared__ __align__(16) double AA[96 * SLAB];   // mode1: frag slabs; mode0: row-major 16x386
    __shared__ __align__(16) float  Wl[64 * WSTR];
    __shared__ float Gl[16 * 66];
    __shared__ float LwR[2 * 8 * 33];

    const int tid  = threadIdx.x;
    const int blk  = blockIdx.x;
    const int grp  = blk & 15;
    const int dir  = grp >> 3;
    const int tile = grp & 7;
    const int hsl  = blk >> 4;
    const int b0   = tile * 16;
    const int u0   = hsl * 16;
    int* mycnt = cnt + grp * 64;

    if (blk == 0 && tid == 0) flags[8] = MAGIC;      // liveness

    const float* Wih = dir ? Wihb : Wihf;
    const float* Whh = dir ? Whhb : Whhf;
    const float* bia = dir ? bb : bf;

    // ---- one-time: W slice into LDS (row c = gate*16+unit, stride 388) ----
    for (int idx = tid; idx < 64 * 384; idx += 512) {
        int c = idx / 384;
        int k = idx - c * 384;
        int grow = (c >> 4) * HH + u0 + (c & 15);
        float v = (k < EE) ? Wih[(size_t)grow * EE + k]
                           : Whh[(size_t)grow * HH + (k - EE)];
        Wl[c * WSTR + k] = v;
    }
    {   // LwR[kk][sub][i2] = lw row (hsl*2+kk), col j = 8*i2+sub (dir half)
        int kk = tid >> 8, sub = (tid >> 5) & 7, i2 = tid & 31;
        LwR[(kk * 8 + sub) * 33 + i2] =
            lw[(size_t)(hsl * 2 + kk) * (2 * HH) + dir * HH + 8 * i2 + sub];
    }

    const int l = tid & 63;
    const int w = tid >> 6;
    const int g    = w & 3;          // gate (mode1)
    const int half = w >> 2;         // K-half (mode1)

    // ---- runtime MFMA layout DISCOVERY (register-only, exact; R12 PASSED) ----
    int mode = 0;
    int rowIdx[4] = {0, 0, 0, 0}, colIdx[4] = {0, 0, 0, 0};
    int mAi = l & 15, kAi = l >> 4, nBi = l & 15, kBi = l >> 4;
    {
        f64x4 z; z[0] = 0.0; z[1] = 0.0; z[2] = 0.0; z[3] = 0.0;
        f64x4 d1 = __builtin_amdgcn_mfma_f64_16x16x4f64((double)l, 1.0, z, 0, 0, 0);
        f64x4 d2 = __builtin_amdgcn_mfma_f64_16x16x4f64(1.0, (double)l, z, 0, 0, 0);
        bool am = true, ak = true, bm = true, bk = true;
        int rm[4], rk[4], cm[4], ck[4];
#pragma unroll
        for (int r = 0; r < 4; ++r) {
            const int v1 = (int)d1[r], v2 = (int)d2[r];
            const bool e1 = ((double)v1 == d1[r]);
            const bool e2 = ((double)v2 == d2[r]);
            rm[r] = (v1 - 96) >> 2;
            am = am && e1 && (((v1 - 96) & 3) == 0) && rm[r] >= 0 && rm[r] < 16;
            rk[r] = (v1 - 6) >> 4;
            ak = ak && e1 && (((v1 - 6) & 15) == 0) && rk[r] >= 0 && rk[r] < 16;
            cm[r] = (v2 - 96) >> 2;
            bm = bm && e2 && (((v2 - 96) & 3) == 0) && cm[r] >= 0 && cm[r] < 16;
            ck[r] = (v2 - 6) >> 4;
            bk = bk && e2 && (((v2 - 6) & 15) == 0) && ck[r] >= 0 && ck[r] < 16;
        }
        const bool Am = (__ballot(am ? 1 : 0) == ~0ull);
        const bool Ak = (__ballot(ak ? 1 : 0) == ~0ull);
        const bool Bm = (__ballot(bm ? 1 : 0) == ~0ull);
        const bool Bk = (__ballot(bk ? 1 : 0) == ~0ull);
        if ((Am || Ak) && (Bm || Bk)) {
            mAi = Am ? (l & 15) : (l >> 2);
            kAi = Am ? (l >> 4) : (l & 3);
            nBi = Bm ? (l & 15) : (l >> 2);
            kBi = Bm ? (l >> 4) : (l & 3);
            f64x4 d3 = __builtin_amdgcn_mfma_f64_16x16x4f64(
                (double)kAi, (double)(1 << kBi), z, 0, 0, 0);
            const bool k34 = (d3[0] == 34.0) && (d3[1] == 34.0) &&
                             (d3[2] == 34.0) && (d3[3] == 34.0);
            if (__ballot(k34 ? 1 : 0) == ~0ull) {
                mode = 1;
#pragma unroll
                for (int r = 0; r < 4; ++r) {
                    rowIdx[r] = Am ? rm[r] : rk[r];
                    colIdx[r] = Bm ? cm[r] : ck[r];
                }
            }
        }
    }

    // ---- scalar-path mapping (R3 verbatim) ----
    const int c = tid & 63;
    const float* WrowL = Wl + c * WSTR;
    const float bias_c = bia[(c >> 4) * HH + u0 + (c & 15)];

    // ---- MFMA-path mapping ----
    const int myIdx = mAi * 4 + kAi;                 // m-major frag index
    const float* Wb = Wl + (g * 16 + nBi) * WSTR + kBi;
    int   glIdx[4];
    float biasv[4];
#pragma unroll
    for (int r = 0; r < 4; ++r) {
        glIdx[r] = rowIdx[r] * 66 + g * 16 + colIdx[r];
        biasv[r] = bia[g * HH + u0 + colIdx[r]];
    }

    const int er = tid >> 4, eu = tid & 15;          // cell mapping (tid<256)
    const int ed = tid >> 3, esub = tid & 7;         // em mapping (tid<256)
    const int erow = ed >> 1, ekk = ed & 1;
    float c_state = 0.f;
    long guard = 0;
    float xgv[2];
    f64x4 Sx, Sh;

    for (int s = 0; s <= TT; ++s) {
        // ---- stage x(s) ----
        if (s < TT) {
            const int t = dir ? (TT - 1 - s) : s;
            const int r = tid >> 5, e4 = tid & 31;
            int tk = tok[(b0 + r) * TT + t];
            float4 v = make_float4(0.f, 0.f, 0.f, 0.f);
            if (tk != 0) v = ((const float4*)(table + (size_t)tk * EE))[e4];
            if (mode) {                              // AA[e4][r*4+q]
                double* dst = AA + e4 * SLAB + r * 4;
                ((double2*)dst)[0] = make_double2((double)v.x, (double)v.y);
                ((double2*)dst)[1] = make_double2((double)v.z, (double)v.w);
            } else {                                 // row-major Ah
                double2* dst = (double2*)(AA + r * 386 + e4 * 4);
                dst[0] = make_double2((double)v.x, (double)v.y);
                dst[1] = make_double2((double)v.z, (double)v.w);
            }
        }
        __syncthreads();

        // ---- x-phase GEMM (before wait; hides inter-block skew) ----
        if (s < TT) {
            if (mode) {
                f64x4 c0; c0[0]=0.0; c0[1]=0.0; c0[2]=0.0; c0[3]=0.0;
                f64x4 c1 = c0;
                const int kb0 = half * 16;
#pragma unroll
                for (int kb = kb0; kb < kb0 + 16; kb += 2) {
                    double a0 = AA[kb * SLAB + myIdx];
                    double b0 = (double)Wb[kb * 4];
                    double a1 = AA[(kb + 1) * SLAB + myIdx];
                    double b1 = (double)Wb[(kb + 1) * 4];
                    c0 = __builtin_amdgcn_mfma_f64_16x16x4f64(a0, b0, c0, 0, 0, 0);
                    c1 = __builtin_amdgcn_mfma_f64_16x16x4f64(a1, b1, c1, 0, 0, 0);
                }
#pragma unroll
                for (int r = 0; r < 4; ++r) Sx[r] = c0[r] + c1[r];
            } else {
                double a0 = 0.0, a1 = 0.0;
                const double* A0 = AA + (2 * w + 0) * 386;
                const double* A1 = AA + (2 * w + 1) * 386;
#pragma unroll 4
                for (int k = 0; k < EE; k += 4) {
                    float4 wf = *((const float4*)(WrowL + k));
                    const double w0 = wf.x, w1 = wf.y, w2 = wf.z, w3 = wf.w;
                    double2 q0, q1;
                    q0 = *((const double2*)(A0 + k)); q1 = *((const double2*)(A0 + k + 2));
                    a0 += q0.x * w0 + q0.y * w1 + q1.x * w2 + q1.y * w3;
                    q0 = *((const double2*)(A1 + k)); q1 = *((const double2*)(A1 + k + 2));
                    a1 += q0.x * w0 + q0.y * w1 + q1.x * w2 + q1.y * w3;
                }
                xgv[0] = __fadd_rn((float)a0, bias_c);
                xgv[1] = __fadd_rn((float)a1, bias_c);
            }
        }

        // ---- wait for h(s-1) (verbatim) ----
        if (s > 0 && tid == 0) {
            const int target = 16 * s;
            while (__hip_atomic_load(mycnt, __ATOMIC_RELAXED,
                                     __HIP_MEMORY_SCOPE_AGENT) < target) {
                __builtin_amdgcn_s_sleep(2);
                if (++guard > 100000000L) {
                    __hip_atomic_store(&flags[10], s, __ATOMIC_RELAXED,
                                       __HIP_MEMORY_SCOPE_AGENT);
                    break;
                }
            }
            __threadfence();                         // acquire
        }
        __syncthreads();

        // ---- stage h(s-1) ----
        if (s == 0) {
            if (mode) {
                for (int i = tid; i < 64 * SLAB; i += 512) AA[32 * SLAB + i] = 0.0;
            } else {
                for (int i = tid; i < 2048; i += 512) {
                    int r = i >> 7, u2 = i & 127;
                    *((double2*)(AA + r * 386 + EE + u2 * 2)) = make_double2(0.0, 0.0);
                }
            }
        } else {
            const int rp = (s & 1) ^ 1;
            int i = tid;
#pragma unroll
            for (int rep = 0; rep < 4; ++rep, i += 512) {
                int r = i >> 7, u2 = i & 127;
                const unsigned long long* p = (const unsigned long long*)
                    (hx + ((size_t)((rp * 2 + dir) * BB + b0 + r)) * HH + u2 * 2);
                unsigned long long raw = __hip_atomic_load(
                    p, __ATOMIC_RELAXED, __HIP_MEMORY_SCOPE_AGENT);
                union { unsigned long long u; float f[2]; } cv; cv.u = raw;
                if (mode) {                          // AA[32+(u2>>1)][r*4 + 2(u2&1) ..+1]
                    double* dst = AA + (32 + (u2 >> 1)) * SLAB + r * 4 + ((u2 & 1) << 1);
                    ((double2*)dst)[0] =
                        make_double2((double)cv.f[0], (double)cv.f[1]);
                } else {
                    *((double2*)(AA + r * 386 + EE + u2 * 2)) =
                        make_double2((double)cv.f[0], (double)cv.f[1]);
                }
            }
        }
        __syncthreads();

        if (s == TT) {
            // ---- final emission em(TT-1), then done ----
            if (tid < 256) {
                const int t_em = dir ? (TT - s) : (s - 1);
                double p = 0.0;
#pragma unroll
                for (int i2 = 0; i2 < 32; ++i2) {
                    const int j = 8 * i2 + esub;
                    double hv = mode
                        ? AA[(32 + (j >> 2)) * SLAB + erow * 4 + (j & 3)]
                        : AA[erow * 386 + EE + j];
                    p += hv * (double)LwR[(ekk * 8 + esub) * 33 + i2];
                }
                p += __shfl_xor(p, 1, 64);
                p += __shfl_xor(p, 2, 64);
                p += __shfl_xor(p, 4, 64);
                if (esub == 0)
                    atomicAdd(em + ((size_t)(b0 + erow) * TT + t_em) * KK + hsl * 2 + ekk, p);
            }
            break;
        }

        // ---- h-phase GEMM; combine halves; Gl = f32(Sx)+b + f32(Sh) ----
        if (mode) {
            f64x4 c0; c0[0]=0.0; c0[1]=0.0; c0[2]=0.0; c0[3]=0.0;
            f64x4 c1 = c0;
            const int kb0 = 32 + half * 32;
#pragma unroll 8
            for (int kb = kb0; kb < kb0 + 32; kb += 2) {
                double a0 = AA[kb * SLAB + myIdx];
                double b0 = (double)Wb[kb * 4];
                double a1 = AA[(kb + 1) * SLAB + myIdx];
                double b1 = (double)Wb[(kb + 1) * 4];
                c0 = __builtin_amdgcn_mfma_f64_16x16x4f64(a0, b0, c0, 0, 0, 0);
                c1 = __builtin_amdgcn_mfma_f64_16x16x4f64(a1, b1, c1, 0, 0, 0);
            }
#pragma unroll
            for (int r = 0; r < 4; ++r) Sh[r] = c0[r] + c1[r];
            if (half) {                              // scratch in consumed x-slabs
#pragma unroll
                for (int r = 0; r < 4; ++r) {
                    double* dst = AA + (((g * 4 + r) * 64 + l) << 1);
                    ((double2*)dst)[0] = make_double2(Sx[r], Sh[r]);
                }
            }
            __syncthreads();                         // scratch ready
            if (!half) {
#pragma unroll
                for (int r = 0; r < 4; ++r) {
                    double2 hi = *((const double2*)(AA + (((g * 4 + r) * 64 + l) << 1)));
                    float t1 = __fadd_rn((float)(Sx[r] + hi.x), biasv[r]);
                    Gl[glIdx[r]] = __fadd_rn(t1, (float)(Sh[r] + hi.y));
                }
            }
        } else {
            double a0 = 0.0, a1 = 0.0;
            const double* A0 = AA + (2 * w + 0) * 386 + EE;
            const double* A1 = AA + (2 * w + 1) * 386 + EE;
            const float* WhL = WrowL + EE;
#pragma unroll 4
            for (int k = 0; k < HH; k += 4) {
                float4 wf = *((const float4*)(WhL + k));
                const double w0 = wf.x, w1 = wf.y, w2 = wf.z, w3 = wf.w;
                double2 q0, q1;
                q0 = *((const double2*)(A0 + k)); q1 = *((const double2*)(A0 + k + 2));
                a0 += q0.x * w0 + q0.y * w1 + q1.x * w2 + q1.y * w3;
                q0 = *((const double2*)(A1 + k)); q1 = *((const double2*)(A1 + k + 2));
                a1 += q0.x * w0 + q0.y * w1 + q1.x * w2 + q1.y * w3;
            }
            __syncthreads();                         // match mode1 barrier count
            Gl[(2 * w + 0) * 66 + c] = __fadd_rn(xgv[0], (float)a0);
            Gl[(2 * w + 1) * 66 + c] = __fadd_rn(xgv[1], (float)a1);
        }
        __syncthreads();                             // Gl ready

        // ---- LSTM cell (f32 lattice, verbatim; threads 0-255) ----
        if (tid < 256) {
            const float gi = Gl[er * 66 +  0 + eu];
            const float gf = Gl[er * 66 + 16 + eu];
            const float gg = Gl[er * 66 + 32 + eu];
            const float go = Gl[er * 66 + 48 + eu];
            const float si = 1.f / (1.f + expf(-gi));
            const float sf = 1.f / (1.f + expf(-gf));
            const float so = 1.f / (1.f + expf(-go));
            const float tg = tanhf(gg);
            const float cnew = __fadd_rn(__fmul_rn(sf, c_state), __fmul_rn(si, tg));
            c_state = cnew;
            const float hval = __fmul_rn(so, tanhf(cnew));
            __hip_atomic_store(
                hx + ((size_t)(((s & 1) * 2 + dir) * BB + b0 + er)) * HH + u0 + eu,
                hval, __ATOMIC_RELAXED, __HIP_MEMORY_SCOPE_AGENT);
        }

        // ---- signal h(s) ready (verbatim) ----
        __syncthreads();     // drains all waves' h stores
        if (tid == 0) {
            __threadfence();                         // release
            __hip_atomic_fetch_add(mycnt, 1, __ATOMIC_RELAXED,
                                   __HIP_MEMORY_SCOPE_AGENT);
        }

        // ---- emission em(s-1): AFTER signal -> hides in next wait slack ----
        if (s >= 1 && tid < 256) {
            const int t_em = dir ? (TT - s) : (s - 1);
            double p = 0.0;
#pragma unroll
            for (int i2 = 0; i2 < 32; ++i2) {
                const int j = 8 * i2 + esub;
                double hv = mode
                    ? AA[(32 + (j >> 2)) * SLAB + erow * 4 + (j & 3)]
                    : AA[erow * 386 + EE + j];
                p += hv * (double)LwR[(ekk * 8 + esub) * 33 + i2];
            }
            p += __shfl_xor(p, 1, 64);
            p += __shfl_xor(p, 2, 64);
            p += __shfl_xor(p, 4, 64);
            if (esub == 0)
                atomicAdd(em + ((size_t)(b0 + erow) * TT + t_em) * KK + hsl * 2 + ekk, p);
        }
    }
}

// ---------------------------------------------------------------------------
// k_viterbi: f32 DP, reference rounding/order (PASSED verbatim).
// ---------------------------------------------------------------------------
__global__ __launch_bounds__(64) void k_viterbi(const double* __restrict__ em,
                                                const float* __restrict__ lb,
                                                const float* __restrict__ startt,
                                                const float* __restrict__ endt,
                                                const float* __restrict__ trans,
                                                int* __restrict__ out) {
    const int b = blockIdx.x;
    const int lane = threadIdx.x;
    const int j = lane & 31, half = lane >> 5;
    __shared__ float trs[32][33];
    __shared__ unsigned char hist[TT][32];
    __shared__ int tags[TT];

    for (int idx = lane; idx < 1024; idx += 64)
        trs[idx >> 5][idx & 31] = trans[idx];
    __syncthreads();

    const float lbj = lb[j];
    const double* emb = em + (size_t)b * TT * KK;
    float score = __fadd_rn(startt[j], __fadd_rn((float)emb[j], lbj));

    for (int t = 1; t < TT; ++t) {
        const float e_cur = __fadd_rn((float)emb[(size_t)t * KK + j], lbj);
        float best = -3.4e38f; int bi = 0;
#pragma unroll
        for (int ii = 0; ii < 16; ++ii) {
            int i = half * 16 + ii;
            float sc_i = __shfl(score, i, 64);
            float c1 = __fadd_rn(sc_i, trs[i][j]);
            float cand = __fadd_rn(c1, e_cur);
            if (cand > best) { best = cand; bi = i; }    // strict > = first max
        }
        float ob = __shfl_xor(best, 32, 64);
        int obi = __shfl_xor(bi, 32, 64);
        if (ob > best || (ob == best && obi < bi)) { best = ob; bi = obi; }
        score = best;
        if (half == 0) hist[t][j] = (unsigned char)bi;
    }

    score = __fadd_rn(score, endt[j]);
    int bj = j; float bs = score;
#pragma unroll
    for (int off = 16; off >= 1; off >>= 1) {
        float os = __shfl_xor(bs, off, 64);
        int oj = __shfl_xor(bj, off, 64);
        if (os > bs || (os == bs && oj < bj)) { bs = os; bj = oj; }
    }
    __syncthreads();
    if (lane == 0) {
        int cur = bj;
        tags[TT - 1] = cur;
        for (int t = TT - 2; t >= 0; --t) { cur = hist[t + 1][cur]; tags[t] = cur; }
    }
    __syncthreads();
    for (int t2 = lane; t2 < TT; t2 += 64) out[b * TT + t2] = tags[t2];
}

// ---------------------------------------------------------------------------
// k_final: failure decode only (healthy runs untouched).
// ---------------------------------------------------------------------------
__global__ __launch_bounds__(64) void k_final(const int* __restrict__ flags,
                                              int* __restrict__ outp) {
    if (threadIdx.x != 0) return;
    if (flags[8] != MAGIC)   outp[0] = 990000;
    else if (flags[10] != 0) outp[0] = 850000 + flags[10] * 64;
}

// ---------------------------------------------------------------------------
extern "C" void kernel_launch(void* const* d_in, const int* in_sizes, int n_in,
                              void* d_out, int out_size, void* d_ws, size_t ws_size,
                              hipStream_t stream) {
    const int*   tok   = (const int*)d_in[0];
    const float* table = (const float*)d_in[3];
    const float* Wihf  = (const float*)d_in[4];
    const float* Whhf  = (const float*)d_in[5];
    const float* bf    = (const float*)d_in[6];
    const float* Wihb  = (const float*)d_in[7];
    const float* Whhb  = (const float*)d_in[8];
    const float* bb    = (const float*)d_in[9];
    const float* lw    = (const float*)d_in[10];
    const float* lb    = (const float*)d_in[11];
    const float* st    = (const float*)d_in[12];
    const float* en    = (const float*)d_in[13];
    const float* tr    = (const float*)d_in[14];

    if (ws_size < (19ull << 20)) return;

    char* ws = (char*)d_ws;
    float*  hx    = (float*)ws;
    int*    cnt   = (int*)(ws + OFF_CNT);
    int*    flags = (int*)(ws + OFF_FLG);
    double* em    = (double*)(ws + OFF_EM);

    hipMemsetAsync(cnt, 0, 8192, stream);            // cnt + flags
    hipMemsetAsync(em, 0, (size_t)BB * TT * KK * 8, stream);
    k_persist<<<256, 512, 0, stream>>>(tok, table, Wihf, Whhf, bf,
                                       Wihb, Whhb, bb, lw, hx, cnt, em, flags);
    k_viterbi<<<BB, 64, 0, stream>>>(em, lb, st, en, tr, (int*)d_out);
    k_final  <<<1, 64, 0, stream>>>(flags, (int*)d_out);
}